// Round 9
// baseline (418.342 us; speedup 1.0000x reference)
//
#include <hip/hip_runtime.h>
#include <hip/hip_bf16.h>
#include <stdint.h>

// Self-attention, B=4, S=2048, D=1024, fp32 in/out.
// R9: EXP GEMM moves to MX-scaled fp8 (e4m3, unit scales) via
//     mfma_scale_f32_16x16x128_f8f6f4 at ~2x bf16 rate, BK=128 (8 K-iters,
//     half the barriers). Q/K stored as e4m3 by proj (UNscaled; the 1/32
//     attention scale is applied inside EXP's epilogue before expf so fp8
//     quantization happens at sigma~0.58, not in the subnormal range).
//     proj (bf16 dual-B, grid 768) / PV (bf16 single, 512 blocks) / cast
//     unchanged from R8 (best verified structure).

typedef float f32x4 __attribute__((ext_vector_type(4)));
typedef short s16x8 __attribute__((ext_vector_type(8)));
typedef int   i32x4 __attribute__((ext_vector_type(4)));
typedef int   i32x8 __attribute__((ext_vector_type(8)));

__device__ __forceinline__ uint16_t f2bf(float f) {
    uint32_t u = __float_as_uint(f);
    u += 0x7fffu + ((u >> 16) & 1u);   // round-to-nearest-even
    return (uint16_t)(u >> 16);
}

__device__ __forceinline__ uint8_t f2fp8(float f) {
    // OCP e4m3fn RNE via HW pack (gfx950)
    int p = __builtin_amdgcn_cvt_pk_fp8_f32(f, f, 0, false);
    return (uint8_t)(p & 0xff);
}

#define GLOAD16(gp, lp)                                                  \
    __builtin_amdgcn_global_load_lds(                                    \
        (const __attribute__((address_space(1))) uint32_t*)(gp),         \
        (__attribute__((address_space(3))) uint32_t*)(lp), 16, 0, 0)

// ---------------------------------------------------------------------------
// Staging swizzle (conflict-free, measured 0 since R4): a 16 KB tile is
// 1024 16-byte slots; slot cs holds row cs>>3, chunk (cs&7)^((cs>>3)&7).
//  - bf16 BK=64 tile: row = 64 elems = 8 chunks; frag read offset
//    (kc^(lr&7))*8 elems, kc = kk*4+(lane>>4).
//  - fp8 BK=128 tile: row = 128 B = 8 chunks; frag = 32 B at chunks
//    {2c^(lr&7), (2c+1)^(lr&7)}, c = lane>>4 (two ds_read_b128).
// C/D layout per 16x16 tile (all dtypes): row=(lane>>4)*4+reg, col=lane&15.
// ---------------------------------------------------------------------------

// Projections, 768 blocks, uniform dual-B bf16 core. id triple: r3=id%3.
//   r3<2 (QK): qkid=g3*2+r3. m=qkid>>3, n=qkid&7. Q,K -> fp8 e4m3 (unscaled).
//   r3==2 (VT): m=g3>>5, npair=g3&31. V^T (bf16) two 128-col tiles + bv(row).
__global__ __launch_bounds__(256, 2) void proj_qkv(
    const uint16_t* __restrict__ xb, const uint16_t* __restrict__ wqb,
    const uint16_t* __restrict__ wkb, const uint16_t* __restrict__ wvb,
    const float* __restrict__ bq, const float* __restrict__ bk,
    const float* __restrict__ bv,
    uint8_t* __restrict__ qb8, uint8_t* __restrict__ kb8,
    uint16_t* __restrict__ vtb)
{
    __shared__ __attribute__((aligned(16))) uint16_t As[128 * 64];
    __shared__ __attribute__((aligned(16))) uint16_t Bs1[128 * 64];
    __shared__ __attribute__((aligned(16))) uint16_t Bs2[128 * 64];

    const int id = blockIdx.x;
    const int g3 = id / 3;
    const int r3 = id - g3 * 3;
    const bool qk = r3 < 2;

    const int t = threadIdx.x;
    const int wave = t >> 6, lane = t & 63;
    const int wm = (wave >> 1) * 64, wn = (wave & 1) * 64;
    const int lr = lane & 15;
    const int lr7 = lr & 7;

    long long row0, col0a, col0b;
    const uint16_t *A, *B1, *B2;
    if (qk) {
        const int qkid = g3 * 2 + r3;
        row0  = (long long)(qkid >> 3) * 128;
        col0a = (long long)(qkid & 7) * 128;
        col0b = col0a;
        A = xb; B1 = wqb; B2 = wkb;
    } else {
        row0  = (long long)(g3 >> 5) * 128;
        col0a = (long long)(g3 & 31) * 256;
        col0b = col0a + 128;
        A = wvb; B1 = xb; B2 = xb;
    }

    const uint16_t* gA[4]; const uint16_t* gB1[4]; const uint16_t* gB2[4];
    uint16_t* lA[4]; uint16_t* lB1[4]; uint16_t* lB2[4];
#pragma unroll
    for (int p = 0; p < 4; ++p) {
        const int cs = p * 256 + wave * 64 + lane;
        const int rr = cs >> 3;
        const int kc = ((cs & 7) ^ (rr & 7)) * 8;
        gA[p]  = A  + (row0  + rr) * 1024 + kc;
        gB1[p] = B1 + (col0a + rr) * 1024 + kc;
        gB2[p] = B2 + (col0b + rr) * 1024 + kc;
        lA[p]  = As  + (p * 256 + wave * 64) * 8;
        lB1[p] = Bs1 + (p * 256 + wave * 64) * 8;
        lB2[p] = Bs2 + (p * 256 + wave * 64) * 8;
    }

    f32x4 acc1[4][4] = {};
    f32x4 acc2[4][4] = {};

    for (int k0 = 0; k0 < 1024; k0 += 64) {
#pragma unroll
        for (int p = 0; p < 4; ++p) GLOAD16(gA[p] + k0, lA[p]);
#pragma unroll
        for (int p = 0; p < 4; ++p) GLOAD16(gB1[p] + k0, lB1[p]);
#pragma unroll
        for (int p = 0; p < 4; ++p) GLOAD16(gB2[p] + k0, lB2[p]);
        __syncthreads();

#pragma unroll
        for (int kk = 0; kk < 2; ++kk) {
            const int lka = ((kk * 4 + (lane >> 4)) ^ lr7) * 8;
            s16x8 a[4], b[4];
#pragma unroll
            for (int i = 0; i < 4; ++i)
                a[i] = *(const s16x8*)(As + (wm + i * 16 + lr) * 64 + lka);
#pragma unroll
            for (int j = 0; j < 4; ++j)
                b[j] = *(const s16x8*)(Bs1 + (wn + j * 16 + lr) * 64 + lka);
#pragma unroll
            for (int i = 0; i < 4; ++i)
#pragma unroll
                for (int j = 0; j < 4; ++j)
                    acc1[i][j] = __builtin_amdgcn_mfma_f32_16x16x32_bf16(
                        a[i], b[j], acc1[i][j], 0, 0, 0);
#pragma unroll
            for (int j = 0; j < 4; ++j)
                b[j] = *(const s16x8*)(Bs2 + (wn + j * 16 + lr) * 64 + lka);
#pragma unroll
            for (int i = 0; i < 4; ++i)
#pragma unroll
                for (int j = 0; j < 4; ++j)
                    acc2[i][j] = __builtin_amdgcn_mfma_f32_16x16x32_bf16(
                        a[i], b[j], acc2[i][j], 0, 0, 0);
        }
        __syncthreads();
    }

    const int rbase = wm + (lane >> 4) * 4;
    const int cbase = wn + lr;
    if (qk) {
#pragma unroll
        for (int i = 0; i < 4; ++i)
#pragma unroll
            for (int rr = 0; rr < 4; ++rr) {
                const long long row = row0 + rbase + i * 16 + rr;
#pragma unroll
                for (int j = 0; j < 4; ++j) {
                    const long long col = col0a + cbase + j * 16;
                    qb8[row * 1024 + col] = f2fp8(acc1[i][j][rr] + bq[col]);
                    kb8[row * 1024 + col] = f2fp8(acc2[i][j][rr] + bk[col]);
                }
            }
    } else {
#pragma unroll
        for (int i = 0; i < 4; ++i)
#pragma unroll
            for (int rr = 0; rr < 4; ++rr) {
                const long long row = row0 + rbase + i * 16 + rr;
                const float bb = bv[row];
#pragma unroll
                for (int j = 0; j < 4; ++j) {
                    const long long ca  = col0a + cbase + j * 16;
                    const long long cb2 = col0b + cbase + j * 16;
                    vtb[row * 8192 + ca]  = f2bf(acc1[i][j][rr] + bb);
                    vtb[row * 8192 + cb2] = f2bf(acc2[i][j][rr] + bb);
                }
            }
    }
}

// EXP: P = exp((Q@K^T)*2^-5) with Q,K in fp8 e4m3, MX MFMA K=128, unit
// scales. Two adjacent 128-col K-tiles per block. grid (16,8,4).
// 8 K-iters of 24 ds_read_b128 + 32 mfma_scale. Fused row-sum atomics.
__global__ __launch_bounds__(256, 2) void gemm_exp(
    const uint8_t* __restrict__ Q, const uint8_t* __restrict__ Km,
    uint16_t* __restrict__ P, float* __restrict__ sums)
{
    __shared__ __attribute__((aligned(16))) uint8_t As8[128 * 128];
    __shared__ __attribute__((aligned(16))) uint8_t Bs1_8[128 * 128];
    __shared__ __attribute__((aligned(16))) uint8_t Bs2_8[128 * 128];

    const int z = blockIdx.z;
    const uint8_t* Ab = Q  + (long long)z * 2048 * 1024;
    const uint8_t* Bb = Km + (long long)z * 2048 * 1024;
    uint16_t* Cb = P + (long long)z * 2048 * 2048;
    float* ax = sums + (long long)z * 2048;

    const int t = threadIdx.x;
    const int wave = t >> 6, lane = t & 63;
    const int wm = (wave >> 1) * 64, wn = (wave & 1) * 64;
    const int lr = lane & 15;
    const int lr7 = lr & 7;
    const long long row0  = (long long)blockIdx.x * 128;
    const long long col0a = (long long)blockIdx.y * 256;
    const long long col0b = col0a + 128;

    // staging: 1024 slots (16B) per 128x128B fp8 tile; slot cs -> row cs>>3,
    // byte chunk ((cs&7)^(rr&7))*16
    const uint8_t* gA[4]; const uint8_t* gB1[4]; const uint8_t* gB2[4];
    uint8_t* lA[4]; uint8_t* lB1[4]; uint8_t* lB2[4];
#pragma unroll
    for (int p = 0; p < 4; ++p) {
        const int cs = p * 256 + wave * 64 + lane;
        const int rr = cs >> 3;
        const int kc = ((cs & 7) ^ (rr & 7)) * 16;
        gA[p]  = Ab + (row0  + rr) * 1024 + kc;
        gB1[p] = Bb + (col0a + rr) * 1024 + kc;
        gB2[p] = Bb + (col0b + rr) * 1024 + kc;
        lA[p]  = As8   + (p * 256 + wave * 64) * 16;
        lB1[p] = Bs1_8 + (p * 256 + wave * 64) * 16;
        lB2[p] = Bs2_8 + (p * 256 + wave * 64) * 16;
    }

    // fragment read offsets: 32B = two 16B chunks {2c^lr7, (2c+1)^lr7}
    const int c2 = (lane >> 4) * 2;
    const int o0 = (c2 ^ lr7) * 16;
    const int o1 = ((c2 + 1) ^ lr7) * 16;

    f32x4 acc1[4][4] = {};
    f32x4 acc2[4][4] = {};

    for (int k0 = 0; k0 < 1024; k0 += 128) {
#pragma unroll
        for (int p = 0; p < 4; ++p) GLOAD16(gA[p] + k0, lA[p]);
#pragma unroll
        for (int p = 0; p < 4; ++p) GLOAD16(gB1[p] + k0, lB1[p]);
#pragma unroll
        for (int p = 0; p < 4; ++p) GLOAD16(gB2[p] + k0, lB2[p]);
        __syncthreads();

        i32x8 a[4], b[4];
#pragma unroll
        for (int i = 0; i < 4; ++i) {
            const uint8_t* pr = As8 + (wm + i * 16 + lr) * 128;
            i32x4 lo = *(const i32x4*)(pr + o0);
            i32x4 hi = *(const i32x4*)(pr + o1);
            a[i] = __builtin_shufflevector(lo, hi, 0, 1, 2, 3, 4, 5, 6, 7);
        }
#pragma unroll
        for (int j = 0; j < 4; ++j) {
            const uint8_t* pr = Bs1_8 + (wn + j * 16 + lr) * 128;
            i32x4 lo = *(const i32x4*)(pr + o0);
            i32x4 hi = *(const i32x4*)(pr + o1);
            b[j] = __builtin_shufflevector(lo, hi, 0, 1, 2, 3, 4, 5, 6, 7);
        }
#pragma unroll
        for (int i = 0; i < 4; ++i)
#pragma unroll
            for (int j = 0; j < 4; ++j)
                acc1[i][j] = __builtin_amdgcn_mfma_scale_f32_16x16x128_f8f6f4(
                    a[i], b[j], acc1[i][j], 0, 0,
                    0, 0x7F7F7F7F, 0, 0x7F7F7F7F);   // unit e8m0 scales
#pragma unroll
        for (int j = 0; j < 4; ++j) {
            const uint8_t* pr = Bs2_8 + (wn + j * 16 + lr) * 128;
            i32x4 lo = *(const i32x4*)(pr + o0);
            i32x4 hi = *(const i32x4*)(pr + o1);
            b[j] = __builtin_shufflevector(lo, hi, 0, 1, 2, 3, 4, 5, 6, 7);
        }
#pragma unroll
        for (int i = 0; i < 4; ++i)
#pragma unroll
            for (int j = 0; j < 4; ++j)
                acc2[i][j] = __builtin_amdgcn_mfma_scale_f32_16x16x128_f8f6f4(
                    a[i], b[j], acc2[i][j], 0, 0,
                    0, 0x7F7F7F7F, 0, 0x7F7F7F7F);
        __syncthreads();
    }

    const int rbase = wm + (lane >> 4) * 4;
    const int cbase = wn + lr;
#pragma unroll
    for (int i = 0; i < 4; ++i)
#pragma unroll
        for (int rr = 0; rr < 4; ++rr) {
            const long long row = row0 + rbase + i * 16 + rr;
            float s = 0.f;
#pragma unroll
            for (int j = 0; j < 4; ++j) {
                const long long ca = col0a + cbase + j * 16;
                const long long cb2 = col0b + cbase + j * 16;
                const float va = __expf(acc1[i][j][rr] * 0.03125f);
                const float vb = __expf(acc2[i][j][rr] * 0.03125f);
                Cb[row * 2048 + ca]  = f2bf(va);
                Cb[row * 2048 + cb2] = f2bf(vb);
                s += va + vb;
            }
            s += __shfl_xor(s, 1);
            s += __shfl_xor(s, 2);
            s += __shfl_xor(s, 4);
            s += __shfl_xor(s, 8);
            if (lr == 0) atomicAdd(&ax[row], s);
        }
}

// PV: out = (P@V) * rcp(sums[row]). bf16, BK=64 single-tile, grid (16,8,4).
__global__ __launch_bounds__(256, 2) void gemm_pv(
    const uint16_t* __restrict__ P, const uint16_t* __restrict__ Vt,
    float* __restrict__ Out, const float* __restrict__ sums)
{
    __shared__ __attribute__((aligned(16))) uint16_t As[128 * 64];
    __shared__ __attribute__((aligned(16))) uint16_t Bs[128 * 64];

    const int z = blockIdx.z;
    const uint16_t* Ab = P + (long long)z * 2048 * 2048;
    const uint16_t* Bb = Vt + (long long)z * 2048;   // col offset in 8192 dim
    float* Cb = Out + (long long)z * 2048 * 1024;
    const float* ax = sums + (long long)z * 2048;

    const int t = threadIdx.x;
    const int wave = t >> 6, lane = t & 63;
    const int wm = (wave >> 1) * 64, wn = (wave & 1) * 64;
    const int lr = lane & 15;
    const int lr7 = lr & 7;
    const long long row0 = (long long)blockIdx.x * 128;
    const long long col0 = (long long)blockIdx.y * 128;

    const uint16_t* gA[4]; const uint16_t* gB[4];
    uint16_t* lA[4]; uint16_t* lB[4];
#pragma unroll
    for (int p = 0; p < 4; ++p) {
        const int cs = p * 256 + wave * 64 + lane;
        const int rr = cs >> 3;
        const int kc = ((cs & 7) ^ (rr & 7)) * 8;
        gA[p] = Ab + (row0 + rr) * 2048 + kc;
        gB[p] = Bb + (col0 + rr) * 8192 + kc;
        lA[p] = As + (p * 256 + wave * 64) * 8;
        lB[p] = Bs + (p * 256 + wave * 64) * 8;
    }

    f32x4 acc[4][4] = {};

    for (int k0 = 0; k0 < 2048; k0 += 64) {
#pragma unroll
        for (int p = 0; p < 4; ++p) GLOAD16(gA[p] + k0, lA[p]);
#pragma unroll
        for (int p = 0; p < 4; ++p) GLOAD16(gB[p] + k0, lB[p]);
        __syncthreads();

#pragma unroll
        for (int kk = 0; kk < 2; ++kk) {
            const int lka = ((kk * 4 + (lane >> 4)) ^ lr7) * 8;
            s16x8 a[4], b[4];
#pragma unroll
            for (int i = 0; i < 4; ++i)
                a[i] = *(const s16x8*)(As + (wm + i * 16 + lr) * 64 + lka);
#pragma unroll
            for (int j = 0; j < 4; ++j)
                b[j] = *(const s16x8*)(Bs + (wn + j * 16 + lr) * 64 + lka);
#pragma unroll
            for (int i = 0; i < 4; ++i)
#pragma unroll
                for (int j = 0; j < 4; ++j)
                    acc[i][j] = __builtin_amdgcn_mfma_f32_16x16x32_bf16(
                        a[i], b[j], acc[i][j], 0, 0, 0);
        }
        __syncthreads();
    }

    const int rbase = wm + (lane >> 4) * 4;
    const int cbase = wn + lr;
#pragma unroll
    for (int i = 0; i < 4; ++i)
#pragma unroll
        for (int rr = 0; rr < 4; ++rr) {
            const long long row = row0 + rbase + i * 16 + rr;
            const float linv = __builtin_amdgcn_rcpf(ax[row]);
#pragma unroll
            for (int j = 0; j < 4; ++j) {
                const long long col = col0 + cbase + j * 16;
                Cb[row * 1024 + col] = acc[i][j][rr] * linv;
            }
        }
}

// One dispatch: cast x (blocks 0..8191), Wq/Wk/Wv (8192..11263), zero sums.
__global__ void cast_all(const float* __restrict__ x, const float* __restrict__ Wq,
                         const float* __restrict__ Wk, const float* __restrict__ Wv,
                         uint16_t* __restrict__ xb, uint16_t* __restrict__ wqb,
                         uint16_t* __restrict__ wkb, uint16_t* __restrict__ wvb,
                         float* __restrict__ sums) {
    const int b = blockIdx.x;
    const float* in;
    uint16_t* out;
    int i;
    if (b < 8192)       { in = x;  out = xb;  i = b * 256 + threadIdx.x; }
    else if (b < 9216)  { in = Wq; out = wqb; i = (b - 8192) * 256 + threadIdx.x; }
    else if (b < 10240) { in = Wk; out = wkb; i = (b - 9216) * 256 + threadIdx.x; }
    else if (b < 11264) { in = Wv; out = wvb; i = (b - 10240) * 256 + threadIdx.x; }
    else {
        int j = (b - 11264) * 256 + threadIdx.x;   // 8 blocks x 256 x float4 = 8192
        ((float4*)sums)[j] = make_float4(0.f, 0.f, 0.f, 0.f);
        return;
    }
    float4 v = ((const float4*)in)[i];
    ushort4 o = make_ushort4(f2bf(v.x), f2bf(v.y), f2bf(v.z), f2bf(v.w));
    ((ushort4*)out)[i] = o;
}

extern "C" void kernel_launch(void* const* d_in, const int* in_sizes, int n_in,
                              void* d_out, int out_size, void* d_ws, size_t ws_size,
                              hipStream_t stream) {
    const float* x  = (const float*)d_in[0];
    const float* Wq = (const float*)d_in[1];
    const float* bq = (const float*)d_in[2];
    const float* Wk = (const float*)d_in[3];
    const float* bk = (const float*)d_in[4];
    const float* Wv = (const float*)d_in[5];
    const float* bv = (const float*)d_in[6];

    // workspace carve (~88 MiB)
    uint8_t* w = (uint8_t*)d_ws;
    uint16_t* xb  = (uint16_t*)w; w += (size_t)8192 * 1024 * 2;
    uint16_t* wqb = (uint16_t*)w; w += (size_t)1024 * 1024 * 2;
    uint16_t* wkb = (uint16_t*)w; w += (size_t)1024 * 1024 * 2;
    uint16_t* wvb = (uint16_t*)w; w += (size_t)1024 * 1024 * 2;
    uint8_t*  qb8 = (uint8_t*)w;  w += (size_t)8192 * 1024;
    uint8_t*  kb8 = (uint8_t*)w;  w += (size_t)8192 * 1024;
    uint16_t* vtb = (uint16_t*)w; w += (size_t)8192 * 1024 * 2;   // [1024][8192]
    uint16_t* pb  = (uint16_t*)w; w += (size_t)4 * 2048 * 2048 * 2;
    float*    sums = (float*)w;  w += (size_t)8192 * 4;

    // casts + zero the exp-sum accumulator (1 dispatch)
    cast_all<<<dim3(11272), dim3(256), 0, stream>>>(x, Wq, Wk, Wv,
                                                    xb, wqb, wkb, wvb, sums);
    // Q & K (fp8 e4m3, unscaled) fused; V^T (bf16) dual col-tiles (768 blocks)
    proj_qkv<<<dim3(768), 256, 0, stream>>>(xb, wqb, wkb, wvb, bq, bk, bv,
                                            qb8, kb8, vtb);
    // P = exp((Q @ K^T)*2^-5) + fused row sums, MX-fp8 K=128 core
    gemm_exp<<<dim3(16, 8, 4), 256, 0, stream>>>(qb8, kb8, pb, sums);
    // out = (P @ V) * rcp(sums), bf16 single-tile, 2 blocks/CU
    gemm_pv<<<dim3(16, 8, 4), 256, 0, stream>>>(pb, vtb, (float*)d_out, sums);
}